// Round 1
// 835.959 us; speedup vs baseline: 1.0377x; 1.0377x over previous
//
#include <hip/hip_runtime.h>
#include <hip/hip_bf16.h>
#include <math.h>

// Problem constants (from reference)
constexpr int cN1  = 10240;
constexpr int cB   = 1024;
constexpr int cE0  = 256000;
constexpr int cE1  = 10240;
constexpr int cIN  = 602;   // IN_C
constexpr int cHID = 256;
constexpr int cOUT = 41;
constexpr int KC   = 1216;  // virtual-concat K: [agg(602) pad->608 | x_tgt(602) pad->608]

typedef __attribute__((ext_vector_type(8))) short short8;  // 8 bf16 (4 VGPRs)
typedef __attribute__((ext_vector_type(4))) float f32x4;   // MFMA 16x16 C/D

__device__ __forceinline__ int lower_bound_dev(const int* __restrict__ a, int n, int v) {
    int l = 0, r = n;
    while (l < r) { int m = (l + r) >> 1; if (a[m] < v) l = m + 1; else r = m; }
    return l;
}

// ---------------------------------------------------------------------------
// Kernel 0a/0b: needed-target flags for layer-0 outputs.
// Layer 1 only reads h[src1[*]] and h[:B]; any other target's aggregation
// (~33% of the 616 MB gather) is dead work. flag[t]=1 iff t<B or t in src1.
// ---------------------------------------------------------------------------
__global__ __launch_bounds__(256) void k_flag_init(unsigned char* __restrict__ flag)
{
    const int i = blockIdx.x * 256 + threadIdx.x;
    if (i < cN1) flag[i] = (i < cB) ? 1 : 0;
}

__global__ __launch_bounds__(256) void k_flag_mark(
    const int* __restrict__ src1, unsigned char* __restrict__ flag)
{
    const int e = blockIdx.x * 256 + threadIdx.x;
    if (e < cE1) flag[src1[e]] = 1;   // racing same-value byte stores: fine
}

// ---------------------------------------------------------------------------
// Kernel 1: layer-0 mean aggregation; writes bf16 concat buffer
//   cat[t][0..601]    = mean_{e: dst0[e]==t} x[src0[e]]   (cols 602..607 = 0)
//   cat[t][608..1209] = x[t]                              (cols 1210..1215 = 0)
// Block per target (dst0 sorted -> contiguous edge range).
// float2 gather (rows are 8B-aligned: 602*4=2408), skip un-needed targets.
// Skipped targets leave cat rows as workspace poison; their h rows are
// computed-garbage but never read (MFMA rows are independent).
// ---------------------------------------------------------------------------
__global__ __launch_bounds__(256) void k_agg0(
    const float* __restrict__ x, const int* __restrict__ src0,
    const int* __restrict__ dst0, const unsigned char* __restrict__ flag,
    __hip_bfloat16* __restrict__ cat)
{
    const int t = blockIdx.x;
    if (!flag[t]) return;             // uniform: no thread reaches barriers
    const int tid = threadIdx.x;
    const int lo  = lower_bound_dev(dst0, cE0, t);
    const int hi  = lower_bound_dev(dst0, cE0, t + 1);
    const int cnt = hi - lo;

    float ax = 0.f, ay = 0.f, bx = 0.f, by = 0.f;
    __shared__ int s_src[256];
    for (int base = lo; base < hi; base += 256) {
        const int n = min(256, hi - base);
        __syncthreads();
        if (tid < n) s_src[tid] = src0[base + tid];
        __syncthreads();
        for (int j = 0; j < n; ++j) {
            const float2* row2 = (const float2*)(x + (long)s_src[j] * cIN);
            const float2 v = row2[tid];                 // floats [2t, 2t+1] -> 0..511
            ax += v.x; ay += v.y;
            if (tid < 45) {                             // floats 512..601
                const float2 w = row2[256 + tid];
                bx += w.x; by += w.y;
            }
        }
    }

    const float inv = 1.f / (float)(cnt > 1 ? cnt : 1);
    __hip_bfloat162* cr2 = (__hip_bfloat162*)(cat + (long)t * KC);  // 608 bf16x2 slots
    const float2*    xr2 = (const float2*)(x + (long)t * cIN);

    // slots [0..255]  = mean cols 0..511
    __hip_bfloat162 m2;
    m2.x = __float2bfloat16(ax * inv); m2.y = __float2bfloat16(ay * inv);
    cr2[tid] = m2;
    // slots [304..559] = x_tgt cols 0..511 (cat cols 608..1119)
    const float2 xv = xr2[tid];
    __hip_bfloat162 c2;
    c2.x = __float2bfloat16(xv.x); c2.y = __float2bfloat16(xv.y);
    cr2[304 + tid] = c2;
    // tails: slots [256..303] = mean cols 512..607 (90 real + 6 pad)
    //        slots [560..607] = x_tgt cols 512..607
    if (tid < 48) {
        float mx = 0.f, my = 0.f, cx = 0.f, cy = 0.f;
        if (tid < 45) {
            mx = bx * inv; my = by * inv;
            const float2 xw = xr2[256 + tid];
            cx = xw.x; cy = xw.y;
        }
        __hip_bfloat162 ta, tb;
        ta.x = __float2bfloat16(mx); ta.y = __float2bfloat16(my);
        tb.x = __float2bfloat16(cx); tb.y = __float2bfloat16(cy);
        cr2[256 + tid] = ta;
        cr2[560 + tid] = tb;
    }
}

// ---------------------------------------------------------------------------
// Kernel 2: build transposed bf16 weights Wt[n][k], n in [0,256), k in [0,1216)
//   k<602 -> W_l0[k][n]; 608<=k<1210 -> W_r0[k-608][n]; else 0
// ---------------------------------------------------------------------------
__global__ __launch_bounds__(256) void k_prep_w(
    const float* __restrict__ Wl, const float* __restrict__ Wr,
    __hip_bfloat16* __restrict__ Wt)
{
    const int idx = blockIdx.x * 256 + threadIdx.x;   // n*KC + k
    const int n = idx / KC, k = idx - n * KC;
    float v = 0.f;
    if (k < cIN)                        v = Wl[(long)k * cHID + n];
    else if (k >= 608 && k < 608 + cIN) v = Wr[(long)(k - 608) * cHID + n];
    Wt[idx] = __float2bfloat16(v);
}

// ---------------------------------------------------------------------------
// Kernel 3: h = relu(cat @ Wt^T + bias)   [10240 x 256], bf16 MFMA.
// 64x64 block tile, 4 waves x (32x32 = 2x2 fragments of 16x16x32).
// blockIdx remap: the 4 n-siblings sharing one 64-row A panel are made
// congruent mod 8 -> same XCD L2 (round-robin dispatch), A fetched once
// per panel instead of 4x (−75 MB HBM).
// ---------------------------------------------------------------------------
__global__ __launch_bounds__(256) void k_gemm(
    const __hip_bfloat16* __restrict__ cat, const __hip_bfloat16* __restrict__ Wt,
    const float* __restrict__ bias, float* __restrict__ h)
{
    const int bid  = blockIdx.x;
    // bijective over [0,640): m_idx = bits 0-2 | bits 5.. <<3 ; n_idx = bits 3-4
    const int m0   = ((bid & 7) | ((bid >> 5) << 3)) * 64;
    const int n0   = ((bid >> 3) & 3) * 64;
    const int tid  = threadIdx.x;
    const int w    = tid >> 6, lane = tid & 63;
    const int wm   = (w & 1) * 32, wn = (w >> 1) * 32;
    const int lrow = lane & 15, quad = lane >> 4;

    __shared__ __hip_bfloat16 As[64 * 32];
    __shared__ __hip_bfloat16 Bs[64 * 32];

    f32x4 acc[2][2] = {};

    // staging: thread loads 16 B of A and 16 B of B per K-step
    const int srow = tid >> 2, schunk = tid & 3;
    const __hip_bfloat16* gA = cat + (long)(m0 + srow) * KC + schunk * 8;
    const __hip_bfloat16* gB = Wt  + (long)(n0 + srow) * KC + schunk * 8;
    __hip_bfloat16* lA = As + srow * 32 + schunk * 8;
    __hip_bfloat16* lB = Bs + srow * 32 + schunk * 8;

    for (int k0 = 0; k0 < KC; k0 += 32) {
        const short8 av = *(const short8*)(gA + k0);
        const short8 bv = *(const short8*)(gB + k0);
        __syncthreads();
        *(short8*)lA = av;
        *(short8*)lB = bv;
        __syncthreads();

        short8 af[2], bf[2];
        #pragma unroll
        for (int f = 0; f < 2; ++f) {
            af[f] = *(const short8*)(As + (wm + f * 16 + lrow) * 32 + quad * 8);
            bf[f] = *(const short8*)(Bs + (wn + f * 16 + lrow) * 32 + quad * 8);
        }
        #pragma unroll
        for (int fm = 0; fm < 2; ++fm)
            #pragma unroll
            for (int fn = 0; fn < 2; ++fn)
                acc[fm][fn] = __builtin_amdgcn_mfma_f32_16x16x32_bf16(
                    af[fm], bf[fn], acc[fm][fn], 0, 0, 0);
    }

    #pragma unroll
    for (int fm = 0; fm < 2; ++fm)
        #pragma unroll
        for (int fn = 0; fn < 2; ++fn) {
            const int col = n0 + wn + fn * 16 + lrow;
            const float b = bias[col];
            #pragma unroll
            for (int r = 0; r < 4; ++r) {
                const int row = m0 + wm + fm * 16 + quad * 4 + r;
                h[(long)row * cHID + col] = fmaxf(acc[fm][fn][r] + b, 0.f);
            }
        }
}

// ---------------------------------------------------------------------------
// Kernel 4: layer-1 mean aggregation (fp32, small)
// ---------------------------------------------------------------------------
__global__ __launch_bounds__(256) void k_agg1(
    const float* __restrict__ h, const int* __restrict__ src1,
    const int* __restrict__ dst1, float* __restrict__ agg1)
{
    const int t   = blockIdx.x;
    const int tid = threadIdx.x;
    const int lo  = lower_bound_dev(dst1, cE1, t);
    const int hi  = lower_bound_dev(dst1, cE1, t + 1);
    const int cnt = hi - lo;

    float a = 0.f;
    __shared__ int s_src[256];
    for (int base = lo; base < hi; base += 256) {
        const int n = min(256, hi - base);
        __syncthreads();
        if (tid < n) s_src[tid] = src1[base + tid];
        __syncthreads();
        for (int j = 0; j < n; ++j) a += h[(long)s_src[j] * cHID + tid];
    }
    agg1[(long)t * cHID + tid] = a / (float)(cnt > 1 ? cnt : 1);
}

// ---------------------------------------------------------------------------
// Kernel 5: out = log_softmax(agg1 @ W_l1 + b_l1 + h[:B] @ W_r1)  (fp32)
// ---------------------------------------------------------------------------
__global__ __launch_bounds__(64) void k_out(
    const float* __restrict__ h,  const float* __restrict__ agg1,
    const float* __restrict__ Wl, const float* __restrict__ bias,
    const float* __restrict__ Wr, float* __restrict__ out)
{
    const int row = blockIdx.x;
    const int tid = threadIdx.x;
    __shared__ float sA[cHID], sH[cHID];
    for (int i = tid; i < cHID; i += 64) {
        sA[i] = agg1[(long)row * cHID + i];
        sH[i] = h[(long)row * cHID + i];
    }
    __syncthreads();

    float v = 0.f;
    if (tid < cOUT) {
        v = bias[tid];
        for (int k = 0; k < cHID; ++k)
            v += sA[k] * Wl[k * cOUT + tid] + sH[k] * Wr[k * cOUT + tid];
    }
    float lg = (tid < cOUT) ? v : -INFINITY;
    float m = lg;
    #pragma unroll
    for (int off = 32; off > 0; off >>= 1) m = fmaxf(m, __shfl_down(m, off));
    m = __shfl(m, 0);
    float e = (tid < cOUT) ? expf(v - m) : 0.f;
    float s = e;
    #pragma unroll
    for (int off = 32; off > 0; off >>= 1) s += __shfl_down(s, off);
    s = __shfl(s, 0);
    if (tid < cOUT) out[(long)row * cOUT + tid] = v - m - logf(s);
}

// ---------------------------------------------------------------------------
extern "C" void kernel_launch(void* const* d_in, const int* in_sizes, int n_in,
                              void* d_out, int out_size, void* d_ws, size_t ws_size,
                              hipStream_t stream)
{
    const float* x    = (const float*)d_in[0];
    const float* Wl0  = (const float*)d_in[1];
    const float* bl0  = (const float*)d_in[2];
    const float* Wr0  = (const float*)d_in[3];
    const float* Wl1  = (const float*)d_in[4];
    const float* bl1  = (const float*)d_in[5];
    const float* Wr1  = (const float*)d_in[6];
    const int*   src0 = (const int*)d_in[7];
    const int*   dst0 = (const int*)d_in[8];
    const int*   src1 = (const int*)d_in[9];
    const int*   dst1 = (const int*)d_in[10];
    float* out = (float*)d_out;

    // Workspace layout (bytes):
    //   cat : N1*KC*2   = 24.90 MB
    //   Wt  : 256*KC*2  =  0.62 MB
    //   h   : N1*256*4  = 10.49 MB
    //   agg1: B*256*4   =  1.05 MB
    //   flag: N1        = 10 KB
    char* ws = (char*)d_ws;
    const size_t szCat = (size_t)cN1 * KC * sizeof(__hip_bfloat16);
    const size_t szWt  = (size_t)cHID * KC * sizeof(__hip_bfloat16);
    const size_t szH   = (size_t)cN1 * cHID * sizeof(float);
    const size_t szA1  = (size_t)cB * cHID * sizeof(float);
    __hip_bfloat16* cat  = (__hip_bfloat16*)(ws);
    __hip_bfloat16* Wt   = (__hip_bfloat16*)(ws + szCat);
    float*          h    = (float*)(ws + szCat + szWt);
    float*          agg1 = (float*)(ws + szCat + szWt + szH);
    unsigned char*  flag = (unsigned char*)(ws + szCat + szWt + szH + szA1);

    k_flag_init<<<cN1 / 256, 256, 0, stream>>>(flag);
    k_flag_mark<<<cE1 / 256, 256, 0, stream>>>(src1, flag);
    k_prep_w<<<(cHID * KC) / 256, 256, 0, stream>>>(Wl0, Wr0, Wt);
    k_agg0<<<cN1, 256, 0, stream>>>(x, src0, dst0, flag, cat);
    k_gemm<<<(cN1 / 64) * 4, 256, 0, stream>>>(cat, Wt, bl0, h);
    k_agg1<<<cB, 256, 0, stream>>>(h, src1, dst1, agg1);
    k_out<<<cB, 64, 0, stream>>>(h, agg1, Wl1, bl1, Wr1, out);
}